// Round 1
// baseline (407.242 us; speedup 1.0000x reference)
//
#include <hip/hip_runtime.h>

// Problem dims (fixed by setup_inputs)
constexpr int Bc = 4, Cc = 128, Hc = 192, Wc = 192;
constexpr int HI = 96, WI = 96;       // half-res inputs
constexpr int NB = 64;                // n_bins
constexpr int NA = 16;                // n_att
constexpr float SCL = 95.0f / 191.0f; // align_corners scale (96->192)

// ---------------------------------------------------------------------------
// K1: h = x + bilinear(pbe); a1 = relu(h@w1^T + b1); att = relu(a1@w2e^T+b2e)+1e-3
// One block per (b, y, 64-px x-tile). 256 threads.
// ---------------------------------------------------------------------------
__global__ __launch_bounds__(256) void k_att(
    const float* __restrict__ x, const float* __restrict__ pbe,
    const float* __restrict__ w1, const float* __restrict__ b1,
    const float* __restrict__ w2, const float* __restrict__ b2,
    float* __restrict__ att)
{
  // w1s: [k=c][n=o] transposed, row pad 132 (16B-aligned rows, 2-way-free reads)
  __shared__ __align__(16) float w1s[128 * 132];   // 67584 B
  __shared__ __align__(16) float h_s[128 * 64];    // 32768 B  A[k][m]
  __shared__ __align__(16) float a1_s[64 * 132];   // 33792 B  [m][n]
  __shared__ __align__(16) float w2s[16 * 132];    //  8448 B  even rows of w2

  const int tid = threadIdx.x;
  const int xg0 = blockIdx.x * 64;
  const int y = blockIdx.y;
  const int b = blockIdx.z;

  // ---- weights -> LDS (one-time; write conflicts acceptable)
  #pragma unroll
  for (int i = 0; i < 64; ++i) {
    const int idx = tid + i * 256;          // 0..16383
    const int o = idx >> 7, c = idx & 127;
    w1s[c * 132 + o] = w1[idx];
  }
  #pragma unroll
  for (int i = 0; i < 8; ++i) {
    const int t = tid + i * 256;            // 0..2047
    const int j = t >> 7, c = t & 127;
    w2s[j * 132 + c] = w2[(2 * j) * 128 + c];   // even rows only
  }

  // ---- stage h tile: h_s[c][px] = x + bilinear(pbe)
  {
    const int px = tid & 63;
    const int c0 = (tid >> 6) * 32;
    const int xg = xg0 + px;
    const float ysf = y * SCL;
    const int y0 = (int)ysf;
    const int y1 = min(y0 + 1, HI - 1);
    const float wy = ysf - (float)y0;
    const float xsf = xg * SCL;
    const int x0 = (int)xsf;
    const int x1 = min(x0 + 1, WI - 1);
    const float wx = xsf - (float)x0;
    const float w00 = (1.f - wx) * (1.f - wy);
    const float w01 = wx * (1.f - wy);
    const float w10 = (1.f - wx) * wy;
    const float w11 = wx * wy;
    const int r00 = y0 * WI + x0, r01 = y0 * WI + x1;
    const int r10 = y1 * WI + x0, r11 = y1 * WI + x1;
    for (int i = 0; i < 32; ++i) {
      const int c = c0 + i;
      const float xv = x[((b * Cc + c) * Hc + y) * Wc + xg];
      const float* p = pbe + (size_t)(b * Cc + c) * (HI * WI);
      const float pe = w00 * p[r00] + w01 * p[r01] + w10 * p[r10] + w11 * p[r11];
      h_s[c * 64 + px] = xv + pe;
    }
  }
  __syncthreads();

  // ---- phase 1 GEMM: C[64m][128n], micro-tile 4m x (4+4)n per thread
  const int tn = tid & 15;
  const int tm = tid >> 4;       // 0..15
  const int m0 = tm * 4;
  const int n0 = tn * 4;         // first n-quad
  const int n1 = 64 + tn * 4;    // second n-quad

  float acc[4][8];
  {
    const float4 bA = *(const float4*)&b1[n0];
    const float4 bB = *(const float4*)&b1[n1];
    #pragma unroll
    for (int mi = 0; mi < 4; ++mi) {
      acc[mi][0] = bA.x; acc[mi][1] = bA.y; acc[mi][2] = bA.z; acc[mi][3] = bA.w;
      acc[mi][4] = bB.x; acc[mi][5] = bB.y; acc[mi][6] = bB.z; acc[mi][7] = bB.w;
    }
  }

  #pragma unroll 4
  for (int k = 0; k < 128; ++k) {
    const float4 av  = *(const float4*)&h_s[k * 64 + m0];
    const float4 bv0 = *(const float4*)&w1s[k * 132 + n0];
    const float4 bv1 = *(const float4*)&w1s[k * 132 + n1];
    const float am[4] = {av.x, av.y, av.z, av.w};
    const float bn[8] = {bv0.x, bv0.y, bv0.z, bv0.w, bv1.x, bv1.y, bv1.z, bv1.w};
    #pragma unroll
    for (int mi = 0; mi < 4; ++mi)
      #pragma unroll
      for (int ni = 0; ni < 8; ++ni)
        acc[mi][ni] = fmaf(am[mi], bn[ni], acc[mi][ni]);
  }

  // relu -> a1_s
  #pragma unroll
  for (int mi = 0; mi < 4; ++mi) {
    float4 v0, v1;
    v0.x = fmaxf(acc[mi][0], 0.f); v0.y = fmaxf(acc[mi][1], 0.f);
    v0.z = fmaxf(acc[mi][2], 0.f); v0.w = fmaxf(acc[mi][3], 0.f);
    v1.x = fmaxf(acc[mi][4], 0.f); v1.y = fmaxf(acc[mi][5], 0.f);
    v1.z = fmaxf(acc[mi][6], 0.f); v1.w = fmaxf(acc[mi][7], 0.f);
    *(float4*)&a1_s[(m0 + mi) * 132 + n0] = v0;
    *(float4*)&a1_s[(m0 + mi) * 132 + n1] = v1;
  }
  __syncthreads();

  // ---- phase 2: att[j] = relu(sum_c a1[c]*w2[2j][c] + b2[2j]) + 1e-3
  {
    const int px = tid >> 2;     // 0..63
    const int jb = tid & 3;      // j = jb + 4*jj
    float aacc[4];
    #pragma unroll
    for (int jj = 0; jj < 4; ++jj) aacc[jj] = b2[2 * (jb + 4 * jj)];

    #pragma unroll 8
    for (int c = 0; c < 128; c += 4) {
      const float4 av = *(const float4*)&a1_s[px * 132 + c];
      #pragma unroll
      for (int jj = 0; jj < 4; ++jj) {
        const int j = jb + 4 * jj;
        const float4 wv = *(const float4*)&w2s[j * 132 + c];
        aacc[jj] += av.x * wv.x + av.y * wv.y + av.z * wv.z + av.w * wv.w;
      }
    }
    const int xg = xg0 + px;
    #pragma unroll
    for (int jj = 0; jj < 4; ++jj) {
      const int j = jb + 4 * jj;
      att[((b * NA + j) * Hc + y) * Wc + xg] = fmaxf(aacc[jj], 0.f) + 0.001f;
    }
  }
}

// ---------------------------------------------------------------------------
// K2: bc = bilinear(prev_bin); delta; out0 = bc+delta; out1 = clip(sort(scale))
// One block per (b, y, 64-px x-tile). 256 threads.
// ---------------------------------------------------------------------------
__global__ __launch_bounds__(256) void k_bins(
    const float* __restrict__ pb, const float* __restrict__ att,
    float* __restrict__ out0, float* __restrict__ out1)
{
  __shared__ float att_s[NA * 64];      // [j][xl]
  __shared__ float srt[NB * 65];        // [k][xl], pad 65 -> conflict-free cols

  const int tid = threadIdx.x;
  const int xg0 = blockIdx.x * 64;
  const int y = blockIdx.y;
  const int b = blockIdx.z;

  // stage att tile
  #pragma unroll
  for (int i = 0; i < 4; ++i) {
    const int t = tid + i * 256;        // 0..1023
    const int j = t >> 6, xl = t & 63;
    att_s[t] = att[((b * NA + j) * Hc + y) * Wc + xg0 + xl];
  }
  __syncthreads();

  const int xl = tid & 63;
  const int kg = tid >> 6;              // 0..3
  const int xg = xg0 + xl;

  const float ysf = y * SCL;
  const int y0 = (int)ysf;
  const int y1 = min(y0 + 1, HI - 1);
  const float wy = ysf - (float)y0;
  const float xsf = xg * SCL;
  const int x0 = (int)xsf;
  const int x1 = min(x0 + 1, WI - 1);
  const float wx = xsf - (float)x0;
  const float w00 = (1.f - wx) * (1.f - wy);
  const float w01 = wx * (1.f - wy);
  const float w10 = (1.f - wx) * wy;
  const float w11 = wx * wy;
  const int r00 = y0 * WI + x0, r01 = y0 * WI + x1;
  const int r10 = y1 * WI + x0, r11 = y1 * WI + x1;

  for (int i = 0; i < 16; ++i) {
    const int k = kg + 4 * i;
    const float* p = pb + (size_t)(b * NB + k) * (HI * WI);
    const float bc = w00 * p[r00] + w01 * p[r01] + w10 * p[r10] + w11 * p[r11];
    float delta = 0.f;
    #pragma unroll
    for (int j = 0; j < NA; ++j) {
      const float d = att_s[j * 64 + xl] - bc;
      const float r = fmaf(300.f * d, d, 1.f);
#if defined(__has_builtin)
#if __has_builtin(__builtin_amdgcn_rcpf)
      delta += d * __builtin_amdgcn_rcpf(r);
#else
      delta += d / r;
#endif
#else
      delta += d / r;
#endif
    }
    const float bnc = bc + delta * (1.f / 16.f);
    out0[((b * NB + k) * Hc + y) * Wc + xg] = bnc;
    srt[k * 65 + xl] = fmaf(9.999f, bnc, 0.001f);
  }
  __syncthreads();

  // bitonic sort along k (64 elems) for each column xl; ascending
  for (int size = 2; size <= 64; size <<= 1) {
    for (int stride = size >> 1; stride >= 1; stride >>= 1) {
      #pragma unroll
      for (int l = 0; l < 8; ++l) {
        const int ce = tid + l * 256;          // 0..2047
        const int col = ce & 63;
        const int p = ce >> 6;                 // 0..31
        const int i = ((p & ~(stride - 1)) << 1) | (p & (stride - 1));
        const int j = i | stride;
        const bool asc = ((i & size) == 0);
        const float a = srt[i * 65 + col];
        const float c = srt[j * 65 + col];
        const float lo = fminf(a, c), hi = fmaxf(a, c);
        srt[i * 65 + col] = asc ? lo : hi;
        srt[j * 65 + col] = asc ? hi : lo;
      }
      __syncthreads();
    }
  }

  for (int i = 0; i < 16; ++i) {
    const int k = kg + 4 * i;
    const float v = fminf(fmaxf(srt[k * 65 + xl], 0.001f), 10.0f);
    out1[((b * NB + k) * Hc + y) * Wc + xg] = v;
  }
}

// ---------------------------------------------------------------------------
extern "C" void kernel_launch(void* const* d_in, const int* in_sizes, int n_in,
                              void* d_out, int out_size, void* d_ws, size_t ws_size,
                              hipStream_t stream) {
  const float* x   = (const float*)d_in[0];   // (4,128,192,192)
  const float* pb  = (const float*)d_in[1];   // (4,64,96,96)
  const float* pbe = (const float*)d_in[2];   // (4,128,96,96)
  const float* w1  = (const float*)d_in[3];   // (128,128)
  const float* b1  = (const float*)d_in[4];   // (128,)
  const float* w2  = (const float*)d_in[5];   // (32,128)
  const float* b2  = (const float*)d_in[6];   // (32,)

  float* out0 = (float*)d_out;                       // bin_new_centers
  float* out1 = out0 + (size_t)Bc * NB * Hc * Wc;    // bin_centers
  float* att  = (float*)d_ws;                        // (4,16,192,192) scratch

  dim3 grid(Wc / 64, Hc, Bc);
  k_att<<<grid, 256, 0, stream>>>(x, pbe, w1, b1, w2, b2, att);
  k_bins<<<grid, 256, 0, stream>>>(pb, att, out0, out1);
}

// Round 2
// 275.449 us; speedup vs baseline: 1.4785x; 1.4785x over previous
//
#include <hip/hip_runtime.h>

// Problem dims (fixed by setup_inputs)
constexpr int Bc = 4, Cc = 128, Hc = 192, Wc = 192;
constexpr int HI = 96, WI = 96;       // half-res inputs
constexpr int NB = 64;                // n_bins
constexpr int NA = 16;                // n_att
constexpr float SCL = 95.0f / 191.0f; // align_corners scale (96->192)

typedef __attribute__((ext_vector_type(8))) short bf16x8;
typedef __attribute__((ext_vector_type(4))) float f32x4;

__device__ __forceinline__ unsigned short f2bf(float f) {
  unsigned u = __builtin_bit_cast(unsigned, f);
  unsigned r = (u + 0x7FFFu + ((u >> 16) & 1u)) >> 16;   // RNE
  return (unsigned short)r;
}

__device__ __forceinline__ float rcp_fast(float r) {
#if defined(__has_builtin)
#if __has_builtin(__builtin_amdgcn_rcpf)
  return __builtin_amdgcn_rcpf(r);
#else
  return 1.0f / r;
#endif
#else
  return 1.0f / r;
#endif
}

// ---------------------------------------------------------------------------
// Prep: w1 (128x128 f32) -> bf16; even rows of w2 (16x128) -> bf16. Into ws.
// ---------------------------------------------------------------------------
__global__ __launch_bounds__(256) void k_prep(
    const float* __restrict__ w1, const float* __restrict__ w2,
    unsigned short* __restrict__ w1bf, unsigned short* __restrict__ w2bf)
{
  const int t = blockIdx.x * 256 + threadIdx.x;   // 0..18431
  if (t < 16384) {
    w1bf[t] = f2bf(w1[t]);
  } else {
    const int u = t - 16384;                      // 0..2047
    const int j = u >> 7, c = u & 127;
    w2bf[u] = f2bf(w2[(2 * j) * 128 + c]);        // even rows only
  }
}

// ---------------------------------------------------------------------------
// K1 (MFMA): h = x + bilinear(pbe);  a1 = relu(h@w1^T+b1);
//            att = relu(a1@w2e^T+b2e)+1e-3  -> att_ws[b][y][x][j]
// One block per (b, y, 64-px x-tile). 256 threads = 4 waves; wave w owns
// m-tile (16 px) w. B-fragments for both GEMMs come straight from global
// bf16 copies (L1-resident, 36 KB).
// ---------------------------------------------------------------------------
__global__ __launch_bounds__(256) void k_att(
    const float* __restrict__ x, const float* __restrict__ pbe,
    const unsigned short* __restrict__ w1bf, const float* __restrict__ b1,
    const unsigned short* __restrict__ w2bf, const float* __restrict__ b2,
    float* __restrict__ att)
{
  constexpr int PH = 136;                       // row pitch (bf16), 272 B = 17*16B
  __shared__ unsigned short h_s[64 * PH];       // A of GEMM1: [px][c]
  __shared__ unsigned short a1_s[64 * PH];      // A of GEMM2: [px][c]

  const int tid = threadIdx.x;
  const int xg0 = blockIdx.x * 64;
  const int y = blockIdx.y;
  const int b = blockIdx.z;

  // ---- stage h tile (fp32 compute -> bf16): thread = (px, 32-channel slab)
  {
    const int px = tid & 63;
    const int c0 = (tid >> 6) * 32;
    const int xg = xg0 + px;
    const float ysf = y * SCL;
    const int y0 = (int)ysf;
    const int y1 = min(y0 + 1, HI - 1);
    const float wy = ysf - (float)y0;
    const float xsf = xg * SCL;
    const int x0 = (int)xsf;
    const int x1 = min(x0 + 1, WI - 1);
    const float wx = xsf - (float)x0;
    const float w00 = (1.f - wx) * (1.f - wy);
    const float w01 = wx * (1.f - wy);
    const float w10 = (1.f - wx) * wy;
    const float w11 = wx * wy;
    const int r00 = y0 * WI + x0, r01 = y0 * WI + x1;
    const int r10 = y1 * WI + x0, r11 = y1 * WI + x1;
    #pragma unroll 8
    for (int i = 0; i < 32; ++i) {
      const int c = c0 + i;
      const float xv = x[((b * Cc + c) * Hc + y) * Wc + xg];
      const float* p = pbe + (size_t)(b * Cc + c) * (HI * WI);
      const float pe = w00 * p[r00] + w01 * p[r01] + w10 * p[r10] + w11 * p[r11];
      h_s[px * PH + c] = f2bf(xv + pe);
    }
  }
  __syncthreads();

  const int lane = tid & 63;
  const int wv = tid >> 6;        // wave id 0..3
  const int ln = lane & 15;       // MFMA row-in-tile (m for A, n for B, col for C)
  const int qd = lane >> 4;       // quad 0..3
  const int m0 = wv * 16;

  // ---- GEMM1: C[64m][128n] = h[64m][128k] * w1[128n][128k]^T
  bf16x8 af[4];
  #pragma unroll
  for (int kt = 0; kt < 4; ++kt)
    af[kt] = *(const bf16x8*)&h_s[(m0 + ln) * PH + kt * 32 + qd * 8];

  f32x4 acc[8];
  #pragma unroll
  for (int nt = 0; nt < 8; ++nt) acc[nt] = f32x4{0.f, 0.f, 0.f, 0.f};

  #pragma unroll
  for (int nt = 0; nt < 8; ++nt) {
    #pragma unroll
    for (int kt = 0; kt < 4; ++kt) {
      const bf16x8 bf = *(const bf16x8*)&w1bf[(nt * 16 + ln) * 128 + kt * 32 + qd * 8];
      acc[nt] = __builtin_amdgcn_mfma_f32_16x16x32_bf16(af[kt], bf, acc[nt], 0, 0, 0);
    }
  }

  // epilogue: relu(+bias) -> a1_s (bf16). Wave writes only its own 16 rows.
  #pragma unroll
  for (int nt = 0; nt < 8; ++nt) {
    const int n = nt * 16 + ln;
    const float bias = b1[n];
    #pragma unroll
    for (int r = 0; r < 4; ++r) {
      const int m = m0 + qd * 4 + r;
      a1_s[m * PH + n] = f2bf(fmaxf(acc[nt][r] + bias, 0.f));
    }
  }
  // no __syncthreads: each wave reads back only rows it wrote (DS in-order/wave)

  // ---- GEMM2: att[64m][16j] = a1[64m][128k] * w2e[16j][128k]^T
  f32x4 acc2 = f32x4{0.f, 0.f, 0.f, 0.f};
  #pragma unroll
  for (int kt = 0; kt < 4; ++kt) {
    const bf16x8 a2 = *(const bf16x8*)&a1_s[(m0 + ln) * PH + kt * 32 + qd * 8];
    const bf16x8 b2f = *(const bf16x8*)&w2bf[ln * 128 + kt * 32 + qd * 8];
    acc2 = __builtin_amdgcn_mfma_f32_16x16x32_bf16(a2, b2f, acc2, 0, 0, 0);
  }
  const float bias2 = b2[2 * ln];
  #pragma unroll
  for (int r = 0; r < 4; ++r) {
    const int px = m0 + qd * 4 + r;
    const float v = fmaxf(acc2[r] + bias2, 0.f) + 0.001f;
    att[((size_t)((b * Hc + y) * Wc) + xg0 + px) * NA + ln] = v;
  }
}

// ---------------------------------------------------------------------------
// K2: thread = pixel. bc = bilinear(pb); delta (16 attractors); out0;
// 64-element bitonic sort entirely in registers; out1.
// Block = 192 threads = one image row (y uniform). Grid (192, 4).
// ---------------------------------------------------------------------------
__global__ __launch_bounds__(192) void k_bins(
    const float* __restrict__ pb, const float* __restrict__ att,
    float* __restrict__ out0, float* __restrict__ out1)
{
  const int xg = threadIdx.x;       // 0..191
  const int y = blockIdx.x;
  const int b = blockIdx.y;

  // att for this pixel: 16 floats, contiguous
  float am[16];
  {
    const float4* ap = (const float4*)(att + ((size_t)((b * Hc + y) * Wc) + xg) * NA);
    const float4 a0 = ap[0], a1 = ap[1], a2 = ap[2], a3 = ap[3];
    am[0] = a0.x;  am[1] = a0.y;  am[2] = a0.z;  am[3] = a0.w;
    am[4] = a1.x;  am[5] = a1.y;  am[6] = a1.z;  am[7] = a1.w;
    am[8] = a2.x;  am[9] = a2.y;  am[10] = a2.z; am[11] = a2.w;
    am[12] = a3.x; am[13] = a3.y; am[14] = a3.z; am[15] = a3.w;
  }

  const float ysf = y * SCL;
  const int y0 = (int)ysf;
  const int y1 = min(y0 + 1, HI - 1);
  const float wy = ysf - (float)y0;
  const float xsf = xg * SCL;
  const int x0 = (int)xsf;
  const int x1 = min(x0 + 1, WI - 1);
  const float wx = xsf - (float)x0;
  const float w00 = (1.f - wx) * (1.f - wy);
  const float w01 = wx * (1.f - wy);
  const float w10 = (1.f - wx) * wy;
  const float w11 = wx * wy;
  const int r00 = y0 * WI + x0, r01 = y0 * WI + x1;
  const int r10 = y1 * WI + x0, r11 = y1 * WI + x1;

  const size_t obase = (size_t)(b * NB) * (Hc * Wc) + (size_t)y * Wc + xg;
  float v[NB];

  #pragma unroll
  for (int k = 0; k < NB; ++k) {
    const float* p = pb + (size_t)(b * NB + k) * (HI * WI);
    const float bc = w00 * p[r00] + w01 * p[r01] + w10 * p[r10] + w11 * p[r11];
    float delta = 0.f;
    #pragma unroll
    for (int j = 0; j < NA; ++j) {
      const float d = am[j] - bc;
      const float r = fmaf(300.f * d, d, 1.f);
      delta = fmaf(d, rcp_fast(r), delta);
    }
    const float bnc = fmaf(delta, 1.f / 16.f, bc);
    out0[obase + (size_t)k * (Hc * Wc)] = bnc;
    v[k] = fmaf(9.999f, bnc, 0.001f);
  }

  // fully-unrolled bitonic sort on 64 registers (ascending)
  #pragma unroll
  for (int size = 2; size <= NB; size <<= 1) {
    #pragma unroll
    for (int stride = size >> 1; stride >= 1; stride >>= 1) {
      #pragma unroll
      for (int i = 0; i < NB; ++i) {
        if ((i & stride) == 0) {
          const int j = i | stride;
          const bool asc = ((i & size) == 0);
          const float a = v[i], c = v[j];
          const float lo = fminf(a, c), hi = fmaxf(a, c);
          v[i] = asc ? lo : hi;
          v[j] = asc ? hi : lo;
        }
      }
    }
  }

  #pragma unroll
  for (int k = 0; k < NB; ++k) {
    out1[obase + (size_t)k * (Hc * Wc)] = fminf(fmaxf(v[k], 0.001f), 10.0f);
  }
}

// ---------------------------------------------------------------------------
extern "C" void kernel_launch(void* const* d_in, const int* in_sizes, int n_in,
                              void* d_out, int out_size, void* d_ws, size_t ws_size,
                              hipStream_t stream) {
  const float* x   = (const float*)d_in[0];   // (4,128,192,192)
  const float* pb  = (const float*)d_in[1];   // (4,64,96,96)
  const float* pbe = (const float*)d_in[2];   // (4,128,96,96)
  const float* w1  = (const float*)d_in[3];   // (128,128)
  const float* b1  = (const float*)d_in[4];   // (128,)
  const float* w2  = (const float*)d_in[5];   // (32,128)
  const float* b2  = (const float*)d_in[6];   // (32,)

  float* out0 = (float*)d_out;                       // bin_new_centers
  float* out1 = out0 + (size_t)Bc * NB * Hc * Wc;    // bin_centers

  // ws layout: [w1bf 32KB][w2bf 4KB][pad to 64KB][att f32 9.4MB]
  unsigned short* w1bf = (unsigned short*)d_ws;
  unsigned short* w2bf = w1bf + 16384;
  float* att = (float*)((char*)d_ws + 65536);        // [b][y][x][j]

  k_prep<<<72, 256, 0, stream>>>(w1, w2, w1bf, w2bf);

  dim3 g1(Wc / 64, Hc, Bc);
  k_att<<<g1, 256, 0, stream>>>(x, pbe, w1bf, b1, w2bf, b2, att);

  dim3 g2(Hc, Bc);
  k_bins<<<g2, 192, 0, stream>>>(pb, att, out0, out1);
}

// Round 3
// 242.613 us; speedup vs baseline: 1.6786x; 1.1353x over previous
//
#include <hip/hip_runtime.h>

// Problem dims (fixed by setup_inputs)
constexpr int Bc = 4, Cc = 128, Hc = 192, Wc = 192;
constexpr int HI = 96, WI = 96;       // half-res inputs
constexpr int NB = 64;                // n_bins
constexpr int NA = 16;                // n_att
constexpr float SCL = 95.0f / 191.0f; // align_corners scale (96->192)

typedef __attribute__((ext_vector_type(8))) short bf16x8;
typedef __attribute__((ext_vector_type(4))) float f32x4;

__device__ __forceinline__ unsigned short f2bf(float f) {
  unsigned u = __builtin_bit_cast(unsigned, f);
  unsigned r = (u + 0x7FFFu + ((u >> 16) & 1u)) >> 16;   // RNE
  return (unsigned short)r;
}

__device__ __forceinline__ float rcp_fast(float r) {
#if defined(__has_builtin)
#if __has_builtin(__builtin_amdgcn_rcpf)
  return __builtin_amdgcn_rcpf(r);
#else
  return 1.0f / r;
#endif
#else
  return 1.0f / r;
#endif
}

// ---------------------------------------------------------------------------
// Prep: w1 (128x128 f32) -> bf16; even rows of w2 (16x128) -> bf16. Into ws.
// ---------------------------------------------------------------------------
__global__ __launch_bounds__(256) void k_prep(
    const float* __restrict__ w1, const float* __restrict__ w2,
    unsigned short* __restrict__ w1bf, unsigned short* __restrict__ w2bf)
{
  const int t = blockIdx.x * 256 + threadIdx.x;   // 0..18431
  if (t < 16384) {
    w1bf[t] = f2bf(w1[t]);
  } else {
    const int u = t - 16384;                      // 0..2047
    const int j = u >> 7, c = u & 127;
    w2bf[u] = f2bf(w2[(2 * j) * 128 + c]);        // even rows only
  }
}

// ---------------------------------------------------------------------------
// K1 (MFMA): h = x + bilinear(pbe);  a1 = relu(h@w1^T+b1);
//            att = relu(a1@w2e^T+b2e)+1e-3  -> att_ws[b][y][x][j]
// One block per (b, y, 64-px x-tile). 256 threads = 4 waves.
// Staging: pbe y-interp rows -> LDS (coalesced), x via float4, pe via ds_read.
// row_s aliases a1_s (dead until after the pre-GEMM barrier).
// ---------------------------------------------------------------------------
__global__ __launch_bounds__(256) void k_att(
    const float* __restrict__ x, const float* __restrict__ pbe,
    const unsigned short* __restrict__ w1bf, const float* __restrict__ b1,
    const unsigned short* __restrict__ w2bf, const float* __restrict__ b2,
    float* __restrict__ att)
{
  constexpr int PH = 136;   // h_s/a1_s row pitch (bf16): 272 B, 16B-aligned rows
  __shared__ __align__(16) unsigned char smem[64 * PH * 2 + 128 * 36 * 4]; // 35840 B
  unsigned short* h_s  = (unsigned short*)smem;                  // [64][PH]
  float*          row_s = (float*)(smem + 64 * PH * 2);          // [128][36]
  unsigned short* a1_s = (unsigned short*)(smem + 64 * PH * 2);  // [64][PH] (aliases row_s)

  const int tid = threadIdx.x;
  const int xg0 = blockIdx.x * 64;
  const int y = blockIdx.y;
  const int b = blockIdx.z;

  const float ysf = y * SCL;
  const int y0 = (int)ysf;
  const int y1 = min(y0 + 1, HI - 1);
  const float wy = ysf - (float)y0;
  const int xi0 = (int)(xg0 * SCL);

  // ---- phase 1: row_s[c][xi] = y-interp of pbe (coalesced loads)
  #pragma unroll
  for (int i = 0; i < 18; ++i) {
    const int f = tid + 256 * i;        // 0..4607
    const int c = f / 36;
    const int xi = f - c * 36;
    const int xgl = min(xi0 + xi, WI - 1);
    const float* p = pbe + (size_t)(b * Cc + c) * (HI * WI);
    const float top = p[y0 * WI + xgl];
    const float bot = p[y1 * WI + xgl];
    row_s[c * 36 + xi] = top + wy * (bot - top);
  }
  __syncthreads();

  // ---- phase 2: h_s[px][c] = bf16(x + x-interp(row_s))  (x via float4)
  #pragma unroll
  for (int i = 0; i < 8; ++i) {
    const int f4 = tid + 256 * i;       // 0..2047
    const int c = f4 >> 4;              // 0..127
    const int q = f4 & 15;              // px quad
    const float4 xv = *(const float4*)&x[((size_t)(b * Cc + c) * Hc + y) * Wc + xg0 + 4 * q];
    const float xa[4] = {xv.x, xv.y, xv.z, xv.w};
    #pragma unroll
    for (int r = 0; r < 4; ++r) {
      const int px = 4 * q + r;
      const float xsf = (float)(xg0 + px) * SCL;
      const int x0 = (int)xsf;
      const float wx = xsf - (float)x0;
      const int xl = x0 - xi0;          // 0..32, xl+1 <= 35
      const float v0 = row_s[c * 36 + xl];
      const float v1 = row_s[c * 36 + xl + 1];
      h_s[px * PH + c] = f2bf(xa[r] + v0 + wx * (v1 - v0));
    }
  }
  __syncthreads();   // h_s complete; row_s now dead -> a1_s may reuse it

  const int lane = tid & 63;
  const int wv = tid >> 6;        // wave id 0..3
  const int ln = lane & 15;
  const int qd = lane >> 4;
  const int m0 = wv * 16;

  // ---- GEMM1: C[64m][128n] = h[64m][128k] * w1[128n][128k]^T
  bf16x8 af[4];
  #pragma unroll
  for (int kt = 0; kt < 4; ++kt)
    af[kt] = *(const bf16x8*)&h_s[(m0 + ln) * PH + kt * 32 + qd * 8];

  f32x4 acc[8];
  #pragma unroll
  for (int nt = 0; nt < 8; ++nt) acc[nt] = f32x4{0.f, 0.f, 0.f, 0.f};

  #pragma unroll
  for (int nt = 0; nt < 8; ++nt) {
    #pragma unroll
    for (int kt = 0; kt < 4; ++kt) {
      const bf16x8 bf = *(const bf16x8*)&w1bf[(nt * 16 + ln) * 128 + kt * 32 + qd * 8];
      acc[nt] = __builtin_amdgcn_mfma_f32_16x16x32_bf16(af[kt], bf, acc[nt], 0, 0, 0);
    }
  }

  // epilogue: relu(+bias) -> a1_s (bf16). Wave writes only its own 16 rows.
  #pragma unroll
  for (int nt = 0; nt < 8; ++nt) {
    const int n = nt * 16 + ln;
    const float bias = b1[n];
    #pragma unroll
    for (int r = 0; r < 4; ++r) {
      const int m = m0 + qd * 4 + r;
      a1_s[m * PH + n] = f2bf(fmaxf(acc[nt][r] + bias, 0.f));
    }
  }
  // no __syncthreads: each wave reads back only rows it wrote (DS in-order/wave)

  // ---- GEMM2: att[64m][16j] = a1[64m][128k] * w2e[16j][128k]^T
  f32x4 acc2 = f32x4{0.f, 0.f, 0.f, 0.f};
  #pragma unroll
  for (int kt = 0; kt < 4; ++kt) {
    const bf16x8 a2 = *(const bf16x8*)&a1_s[(m0 + ln) * PH + kt * 32 + qd * 8];
    const bf16x8 b2f = *(const bf16x8*)&w2bf[ln * 128 + kt * 32 + qd * 8];
    acc2 = __builtin_amdgcn_mfma_f32_16x16x32_bf16(a2, b2f, acc2, 0, 0, 0);
  }
  const float bias2 = b2[2 * ln];
  #pragma unroll
  for (int r = 0; r < 4; ++r) {
    const int px = m0 + qd * 4 + r;
    const float v = fmaxf(acc2[r] + bias2, 0.f) + 0.001f;
    att[((size_t)((b * Hc + y) * Wc) + xg0 + px) * NA + ln] = v;
  }
}

// ---------------------------------------------------------------------------
// K2: block = one image row (192 threads), thread = pixel.
// pb rows for all 64 bins staged to LDS (coalesced float4), bc from LDS,
// delta (16 attractors), out0, register bitonic sort, out1.
// ---------------------------------------------------------------------------
__global__ __launch_bounds__(192) void k_bins(
    const float* __restrict__ pb, const float* __restrict__ att,
    float* __restrict__ out0, float* __restrict__ out1)
{
  __shared__ __align__(16) float pbs[NB][2][WI];   // 48 KB

  const int tid = threadIdx.x;      // = xg
  const int y = blockIdx.x;
  const int b = blockIdx.y;

  const float ysf = y * SCL;
  const int y0 = (int)ysf;
  const int y1 = min(y0 + 1, HI - 1);
  const float wy = ysf - (float)y0;

  // ---- stage pb rows y0,y1 for all 64 bins: 3072 float4, 16 per thread
  #pragma unroll
  for (int i = 0; i < 16; ++i) {
    const int u = tid + 192 * i;          // 0..3071
    const int k = u / 48;
    const int rem = u - k * 48;
    const int r = rem / 24;
    const int xi4 = rem - r * 24;
    const int yr = r ? y1 : y0;
    const float4 v = *(const float4*)&pb[(size_t)(b * NB + k) * (HI * WI) + yr * WI + xi4 * 4];
    *(float4*)&pbs[k][r][xi4 * 4] = v;
  }

  // att for this pixel: 16 floats, contiguous (overlap with staging)
  float am[16];
  {
    const float4* ap = (const float4*)(att + ((size_t)((b * Hc + y) * Wc) + tid) * NA);
    const float4 a0 = ap[0], a1 = ap[1], a2 = ap[2], a3 = ap[3];
    am[0] = a0.x;  am[1] = a0.y;  am[2] = a0.z;  am[3] = a0.w;
    am[4] = a1.x;  am[5] = a1.y;  am[6] = a1.z;  am[7] = a1.w;
    am[8] = a2.x;  am[9] = a2.y;  am[10] = a2.z; am[11] = a2.w;
    am[12] = a3.x; am[13] = a3.y; am[14] = a3.z; am[15] = a3.w;
  }
  __syncthreads();

  const float xsf = tid * SCL;
  const int x0 = (int)xsf;          // <= 94
  const float wx = xsf - (float)x0;

  const size_t obase = (size_t)(b * NB) * (Hc * Wc) + (size_t)y * Wc + tid;
  float v[NB];

  #pragma unroll
  for (int k = 0; k < NB; ++k) {
    const float v00 = pbs[k][0][x0], v01 = pbs[k][0][x0 + 1];
    const float v10 = pbs[k][1][x0], v11 = pbs[k][1][x0 + 1];
    const float top = v00 + wx * (v01 - v00);
    const float bot = v10 + wx * (v11 - v10);
    const float bc = top + wy * (bot - top);
    float delta = 0.f;
    #pragma unroll
    for (int j = 0; j < NA; ++j) {
      const float d = am[j] - bc;
      const float rq = fmaf(300.f * d, d, 1.f);
      delta = fmaf(d, rcp_fast(rq), delta);
    }
    const float bnc = fmaf(delta, 1.f / 16.f, bc);
    out0[obase + (size_t)k * (Hc * Wc)] = bnc;
    v[k] = fmaf(9.999f, bnc, 0.001f);
  }

  // fully-unrolled bitonic sort on 64 registers (ascending)
  #pragma unroll
  for (int size = 2; size <= NB; size <<= 1) {
    #pragma unroll
    for (int stride = size >> 1; stride >= 1; stride >>= 1) {
      #pragma unroll
      for (int i = 0; i < NB; ++i) {
        if ((i & stride) == 0) {
          const int j = i | stride;
          const bool asc = ((i & size) == 0);
          const float a = v[i], c = v[j];
          const float lo = fminf(a, c), hi = fmaxf(a, c);
          v[i] = asc ? lo : hi;
          v[j] = asc ? hi : lo;
        }
      }
    }
  }

  #pragma unroll
  for (int k = 0; k < NB; ++k) {
    out1[obase + (size_t)k * (Hc * Wc)] = fminf(fmaxf(v[k], 0.001f), 10.0f);
  }
}

// ---------------------------------------------------------------------------
extern "C" void kernel_launch(void* const* d_in, const int* in_sizes, int n_in,
                              void* d_out, int out_size, void* d_ws, size_t ws_size,
                              hipStream_t stream) {
  const float* x   = (const float*)d_in[0];   // (4,128,192,192)
  const float* pb  = (const float*)d_in[1];   // (4,64,96,96)
  const float* pbe = (const float*)d_in[2];   // (4,128,96,96)
  const float* w1  = (const float*)d_in[3];   // (128,128)
  const float* b1  = (const float*)d_in[4];   // (128,)
  const float* w2  = (const float*)d_in[5];   // (32,128)
  const float* b2  = (const float*)d_in[6];   // (32,)

  float* out0 = (float*)d_out;                       // bin_new_centers
  float* out1 = out0 + (size_t)Bc * NB * Hc * Wc;    // bin_centers

  // ws layout: [w1bf 32KB][w2bf 4KB][pad to 64KB][att f32 9.4MB]
  unsigned short* w1bf = (unsigned short*)d_ws;
  unsigned short* w2bf = w1bf + 16384;
  float* att = (float*)((char*)d_ws + 65536);        // [b][y][x][j]

  k_prep<<<72, 256, 0, stream>>>(w1, w2, w1bf, w2bf);

  dim3 g1(Wc / 64, Hc, Bc);
  k_att<<<g1, 256, 0, stream>>>(x, pbe, w1bf, b1, w2bf, b2, att);

  dim3 g2(Hc, Bc);
  k_bins<<<g2, 192, 0, stream>>>(pb, att, out0, out1);
}